// Round 4
// baseline (9456.968 us; speedup 1.0000x reference)
//
#include <hip/hip_runtime.h>
#include <hip/hip_bf16.h>
#include <hip/hip_cooperative_groups.h>

namespace cg = cooperative_groups;

#define DT 0.1f
#define TAU_HP 12.3f
#define TAU_LP 2.3f
#define SCAN_B 1024

// Radix-build parameters: bucket = tgt >> BSHIFT (128 targets/bucket).
#define BSHIFT 7
#define BMASK 127
#define BMAX 2048          // max buckets supported (n_neurons <= 262144)
#define CHUNK 32768        // edges per block in hist/bin passes
#define B4_CAP 6144        // max records per bucket in finalize

// ---------------------------------------------------------------------------
// R1: atomics removed from steady state via CSR-by-target.
// R2: CSR-vector gather (coalesced int4 edge loads, shfl reduce).
// R3: zero-global-atomic radix build (bhist->scan->bin->finalize).
// R4: fused step kernel + Tm1-target edges dropped at build.
// R5: thread remap (1 thr/Tm1 row, 8 lanes/gather row). MEASURED NEUTRAL
//     (1876 vs 1836 us) -> step loop is NOT wave-slot-bound.
// R6: ALL 50 steps fused into ONE cooperative persistent kernel with
//     grid.sync() between steps. Tests the dispatch-gap theory (50 small
//     launches x ~5-15us gap) and surfaces steady-state counters (the
//     per-step phase was invisible below the top-5 cutoff; bin_kernel at
//     137us was the top dispatch = only 7% of total).
//     Grid 1024x256, __launch_bounds__(256,4): 4 blocks/CU residency needs
//     only VGPR<=128 -> cooperative residency check cannot fail.
//     Identical per-row arithmetic (same 8-lane groups + shfl order).
// ---------------------------------------------------------------------------

__global__ void init_kernel(float* __restrict__ vA,
                            float* __restrict__ tm1_f,
                            int n_neurons, int n_tm1) {
    int i = blockIdx.x * blockDim.x + threadIdx.x;
    if (i < n_neurons) vA[i] = 0.0f;
    if (i < n_tm1) tm1_f[i] = 0.0f;
}

// --- build pass 1: per-(block,bucket) histogram (Tm1 targets dropped) --------
__global__ void bhist_kernel(const int* __restrict__ tgt, int* __restrict__ blkhist,
                             int n_edges, int n_tm1, int nb, int nblk) {
    __shared__ int hist[BMAX];
    int b = blockIdx.x;
    for (int i = threadIdx.x; i < nb; i += blockDim.x) hist[i] = 0;
    __syncthreads();
    int base = b * CHUNK;
    int end = min(base + CHUNK, n_edges);
    for (int k = base + threadIdx.x; k < end; k += blockDim.x) {
        int t = tgt[k];
        if (t >= n_tm1) atomicAdd(&hist[t >> BSHIFT], 1);
    }
    __syncthreads();
    for (int i = threadIdx.x; i < nb; i += blockDim.x)
        blkhist[(size_t)i * nblk + b] = hist[i];      // bucket-major for scan
}

// --- 3-level exclusive scan --------------------------------------------------
__global__ void scan1_kernel(const int* in, int* out, int* bsums, int n) {
    __shared__ int s[SCAN_B];
    int gid = blockIdx.x * SCAN_B + threadIdx.x;
    int x = (gid < n) ? in[gid] : 0;
    s[threadIdx.x] = x;
    __syncthreads();
    for (int off = 1; off < SCAN_B; off <<= 1) {
        int t = (threadIdx.x >= off) ? s[threadIdx.x - off] : 0;
        __syncthreads();
        s[threadIdx.x] += t;
        __syncthreads();
    }
    if (gid < n) out[gid] = s[threadIdx.x] - x;       // exclusive
    if (threadIdx.x == SCAN_B - 1) bsums[blockIdx.x] = s[SCAN_B - 1];
}

__global__ void scan2_kernel(int* bsums, int nb, int* total) {
    __shared__ int s[SCAN_B];
    int x = (threadIdx.x < nb) ? bsums[threadIdx.x] : 0;
    s[threadIdx.x] = x;
    __syncthreads();
    for (int off = 1; off < SCAN_B; off <<= 1) {
        int t = (threadIdx.x >= off) ? s[threadIdx.x - off] : 0;
        __syncthreads();
        s[threadIdx.x] += t;
        __syncthreads();
    }
    if (threadIdx.x == nb - 1) *total = s[threadIdx.x];   // inclusive grand total
    if (threadIdx.x < nb) bsums[threadIdx.x] = s[threadIdx.x] - x;
}

__global__ void scanadd_kernel(int* data, const int* __restrict__ bsums, int n) {
    int gid = blockIdx.x * blockDim.x + threadIdx.x;
    if (gid < n) data[gid] += bsums[gid / SCAN_B];
}

// --- build pass 2: bin kept edges into bucket order (LDS cursors) ------------
// record = (src | tlow<<18, weight-bits); src < 2^18, tlow 7 bits.
__global__ void bin_kernel(const int* __restrict__ src, const int* __restrict__ tgt,
                           const float* __restrict__ w, const int* __restrict__ scanned,
                           int2* __restrict__ edges, int n_edges, int n_tm1,
                           int nb, int nblk) {
    __shared__ int cur[BMAX];
    int b = blockIdx.x;
    for (int i = threadIdx.x; i < nb; i += blockDim.x)
        cur[i] = scanned[(size_t)i * nblk + b];
    __syncthreads();
    int base = b * CHUNK;
    int end = min(base + CHUNK, n_edges);
    for (int k = base + threadIdx.x; k < end; k += blockDim.x) {
        int t = tgt[k];
        if (t < n_tm1) continue;                      // dead edges (dv[:tm1]=0)
        int pos = atomicAdd(&cur[t >> BSHIFT], 1);    // LDS atomic
        edges[pos] = make_int2(src[k] | ((t & BMASK) << 18), __float_as_int(w[k]));
    }
}

// --- build pass 3: per-bucket finalize, entirely in LDS, in-place ------------
__global__ void finalize_kernel(int2* edges, const int* __restrict__ scanned,
                                int* __restrict__ row_start,
                                const int* __restrict__ total,
                                int n_neurons, int nb, int nblk) {
    __shared__ int2 buf[B4_CAP];
    __shared__ int hist[BMASK + 1], ls[BMASK + 1], cur[BMASK + 1];
    int b = blockIdx.x;
    int n_kept = *total;
    int beg = scanned[(size_t)b * nblk];
    int end = (b == nb - 1) ? n_kept : scanned[(size_t)(b + 1) * nblk];
    int n = min(end - beg, B4_CAP);

    for (int k = threadIdx.x; k < n; k += blockDim.x) buf[k] = edges[beg + k];
    if (threadIdx.x <= BMASK) hist[threadIdx.x] = 0;
    __syncthreads();
    for (int k = threadIdx.x; k < n; k += blockDim.x)
        atomicAdd(&hist[(buf[k].x >> 18) & BMASK], 1);
    __syncthreads();
    if (threadIdx.x <= BMASK) ls[threadIdx.x] = hist[threadIdx.x];
    __syncthreads();
    for (int off = 1; off <= BMASK; off <<= 1) {
        int t = (threadIdx.x <= BMASK && threadIdx.x >= off) ? ls[threadIdx.x - off] : 0;
        __syncthreads();
        if (threadIdx.x <= BMASK) ls[threadIdx.x] += t;   // inclusive
        __syncthreads();
    }
    if (threadIdx.x <= BMASK) {
        int excl = ls[threadIdx.x] - hist[threadIdx.x];
        cur[threadIdx.x] = excl;
        int t = (b << BSHIFT) + threadIdx.x;
        if (t < n_neurons) row_start[t] = beg + excl;
    }
    if (b == nb - 1 && threadIdx.x == 0) row_start[n_neurons] = n_kept;
    __syncthreads();
    for (int k = threadIdx.x; k < n; k += blockDim.x) {
        int2 r = buf[k];
        int pos = atomicAdd(&cur[(r.x >> 18) & BMASK], 1);  // LDS atomic
        edges[beg + pos] = make_int2(r.x & 0x3FFFF, r.y);
    }
}

// --- fused ALL-STEPS cooperative kernel --------------------------------------
// Work items per step: [0, n_tm1)               -> 1 thread per Tm1 row
//                      [gbase, gbase+8*nrows)   -> 8 lanes per gather row
// gbase mult of 64, n_tm1 mult of 8, WQ mult of 8 -> 8-lane shfl groups never
// split across the grid-stride boundary or the region boundaries.
// grid.sync() is the inter-step barrier (replaces 50 kernel boundaries).
__global__ __launch_bounds__(256, 4)
void steps_kernel(const int* __restrict__ row_start,
                  const int2* __restrict__ edges,
                  float* __restrict__ vA,
                  float* __restrict__ vB,
                  float* __restrict__ tm1_f,
                  const float* __restrict__ tm1_input,
                  const float* __restrict__ tau,
                  const float* __restrict__ vrest,
                  float* __restrict__ out,
                  int n_neurons, int n_tm1, int gbase, int steps) {
    cg::grid_group grid = cg::this_grid();
    const int gtid = blockIdx.x * blockDim.x + threadIdx.x;
    const int gstride = gridDim.x * blockDim.x;
    const int WQ = gbase + 8 * (n_neurons - n_tm1);

    for (int k = 0; k < steps; ++k) {
        const float* vr = (k & 1) ? vB : vA;
        float* vw = (k == steps - 1) ? out : ((k & 1) ? vA : vB);
        const float* x = tm1_input + (size_t)k * n_tm1;
        const int last = (k == steps - 1);

        for (int g = gtid; g < WQ; g += gstride) {
            if (g < n_tm1) {                 // Tm1 row: filter update only
                float cur = vr[g];           // = tm1_v at step k
                if (last) {
                    vw[g] = cur;             // ref: v[:tm1] = old tm1_v
                } else {
                    float f  = tm1_f[g];
                    float xk = x[g];
                    float hp = xk - f;
                    tm1_f[g] = f + DT * (xk - f) / TAU_HP;
                    vw[g] = cur + DT * (fmaxf(hp, 0.0f) - cur) / TAU_LP;
                }
                continue;
            }
            if (g < gbase) continue;         // alignment pad

            int t = g - gbase;
            int row = n_tm1 + (t >> 3);
            int lane = t & 7;

            int s = row_start[row];
            int e = row_start[row + 1];
            float sum = 0.0f;
            for (int p = (s & ~1) + 2 * lane; p < e; p += 16) {
                int4 q = *(const int4*)(edges + p);  // 16B aligned (p even)
                if (p >= s)    sum += fmaxf(vr[q.x], 0.0f) * __int_as_float(q.y);
                if (p + 1 < e) sum += fmaxf(vr[q.z], 0.0f) * __int_as_float(q.w);
            }
            sum += __shfl_xor(sum, 4);
            sum += __shfl_xor(sum, 2);
            sum += __shfl_xor(sum, 1);
            if (lane == 0) {
                float vi = vr[row];
                vw[row] = vi + DT * ((-vi + sum + vrest[row]) / tau[row]);
            }
        }
        grid.sync();
    }
}

extern "C" void kernel_launch(void* const* d_in, const int* in_sizes, int n_in,
                              void* d_out, int out_size, void* d_ws, size_t ws_size,
                              hipStream_t stream) {
    const float* tm1_input  = (const float*)d_in[0];
    const float* weights    = (const float*)d_in[1];
    const float* tau        = (const float*)d_in[2];
    const float* vrest      = (const float*)d_in[3];
    const int*   source_idx = (const int*)d_in[4];
    const int*   target_idx = (const int*)d_in[5];

    const int n_edges   = in_sizes[1];
    const int n_neurons = in_sizes[2];
    const int n_tm1     = 25000;
    const int steps     = in_sizes[0] / n_tm1;

    const int nb   = (n_neurons + BMASK) >> BSHIFT;          // 1563 buckets
    const int nblk = (n_edges + CHUNK - 1) / CHUNK;          // 196 blocks
    const int n_scan = nb * nblk;                            // 306,348

    // Workspace (4-byte units). edges first -> 16B aligned for int4 gather.
    size_t off = 0;
    auto alloc = [&](size_t n) { size_t o = off; off += n; return o; };
    int* ws_i = (int*)d_ws;
    float* ws_f = (float*)d_ws;

    int2*  edges     = (int2*)(ws_i + alloc((size_t)(n_edges + 2) * 2));
    float* vA        = ws_f + alloc(n_neurons);
    float* vB        = ws_f + alloc(n_neurons);
    float* tm1_f     = ws_f + alloc(n_tm1);
    int*   row_start = ws_i + alloc(n_neurons + 1);
    int*   blkhist   = ws_i + alloc((size_t)n_scan);
    int*   bsums     = ws_i + alloc(SCAN_B);
    int*   total     = ws_i + alloc(1);
    (void)ws_size;

    float* out = (float*)d_out;

    const int B = 256;
    const int gridN = (n_neurons + B - 1) / B;
    const int nScanBlocks = (n_scan + SCAN_B - 1) / SCAN_B;  // 300 <= 1024
    const int gridSA = (n_scan + B - 1) / B;

    // Step-kernel work map: Tm1 rows 1:1, then wave-aligned 8-lane groups.
    const int gbase = (n_tm1 + 63) & ~63;

    // --- one-time (per launch) CSR build: zero global atomics ---
    init_kernel<<<gridN, B, 0, stream>>>(vA, tm1_f, n_neurons, n_tm1);
    bhist_kernel<<<nblk, 1024, 0, stream>>>(target_idx, blkhist, n_edges, n_tm1,
                                            nb, nblk);
    scan1_kernel<<<nScanBlocks, SCAN_B, 0, stream>>>(blkhist, blkhist, bsums, n_scan);
    scan2_kernel<<<1, SCAN_B, 0, stream>>>(bsums, nScanBlocks, total);
    scanadd_kernel<<<gridSA, B, 0, stream>>>(blkhist, bsums, n_scan);
    bin_kernel<<<nblk, 1024, 0, stream>>>(source_idx, target_idx, weights, blkhist,
                                          edges, n_edges, n_tm1, nb, nblk);
    finalize_kernel<<<nb, 1024, 0, stream>>>(edges, blkhist, row_start, total,
                                             n_neurons, nb, nblk);

    // --- steady state: ONE cooperative kernel for all 50 steps ---
    // 1024 blocks x 256 thr = 4 blocks/CU residency (VGPR<=128 suffices).
    int nn = n_neurons, nt = n_tm1, gb = gbase, st = steps;
    void* args[] = {
        (void*)&row_start, (void*)&edges, (void*)&vA, (void*)&vB,
        (void*)&tm1_f, (void*)&tm1_input, (void*)&tau, (void*)&vrest,
        (void*)&out, (void*)&nn, (void*)&nt, (void*)&gb, (void*)&st
    };
    hipLaunchCooperativeKernel((void*)steps_kernel, dim3(1024), dim3(256),
                               args, 0, stream);
}

// Round 5
// 2179.587 us; speedup vs baseline: 4.3389x; 4.3389x over previous
//
#include <hip/hip_runtime.h>
#include <hip/hip_bf16.h>

#define DT 0.1f
#define TAU_HP 12.3f
#define TAU_LP 2.3f
#define SCAN_B 1024

// Radix-build parameters: bucket = tgt >> BSHIFT (128 targets/bucket).
#define BSHIFT 7
#define BMASK 127
#define BMAX 2048          // max buckets supported (n_neurons <= 262144)
#define CHUNK 32768        // edges per block in hist/bin passes
#define B4_CAP 6144        // max records per bucket in finalize

// ---------------------------------------------------------------------------
// R1-R4: CSR-by-target, zero-atomic radix build, fused per-step kernel,
//        Tm1-target edges dropped.
// R5: 1 thr/Tm1 row + 8 lanes/gather row. MEASURED NEUTRAL (1876 vs 1836)
//     -> step is NOT wave-slot-bound; invariant = 5.6M random vr gathers.
// R6: cooperative all-steps kernel. MEASURED 9457us (5x WORSE): grid.sync
//     across XCDs ~100+us each + starved TLP. REVERTED to per-step launches.
// R7: relu-activity bitmask skip. bit[i] = (v[i] > 0). Readers test the bit
//     (25KB array -> L1-resident, no L2 request) and gather vr only when set:
//     exec-masked lanes issue no L2 requests -> ~50% fewer gather requests
//     (theory: step is L2-request-rate-bound). Bitwise-identical numerics
//     (skipped terms are exactly 0; bit==1 implies relu(v)=v).
//     Triple-buffered mask: step k writes M[k%3], reads M[(k+2)%3] (prev
//     step's), clears M[(k+1)%3] (idle this step). Ballot-compressed writes:
//     1 atomicOr per wave. v0=0 -> step0 reads all-zero mask = correct.
// ---------------------------------------------------------------------------

__global__ void init_kernel(float* __restrict__ vA,
                            float* __restrict__ tm1_f,
                            unsigned* __restrict__ mask3,
                            int n_neurons, int n_tm1, int mask3_words) {
    int i = blockIdx.x * blockDim.x + threadIdx.x;
    if (i < n_neurons) vA[i] = 0.0f;
    if (i < n_tm1) tm1_f[i] = 0.0f;
    if (i < mask3_words) mask3[i] = 0u;
}

// --- build pass 1: per-(block,bucket) histogram (Tm1 targets dropped) --------
__global__ void bhist_kernel(const int* __restrict__ tgt, int* __restrict__ blkhist,
                             int n_edges, int n_tm1, int nb, int nblk) {
    __shared__ int hist[BMAX];
    int b = blockIdx.x;
    for (int i = threadIdx.x; i < nb; i += blockDim.x) hist[i] = 0;
    __syncthreads();
    int base = b * CHUNK;
    int end = min(base + CHUNK, n_edges);
    for (int k = base + threadIdx.x; k < end; k += blockDim.x) {
        int t = tgt[k];
        if (t >= n_tm1) atomicAdd(&hist[t >> BSHIFT], 1);
    }
    __syncthreads();
    for (int i = threadIdx.x; i < nb; i += blockDim.x)
        blkhist[(size_t)i * nblk + b] = hist[i];      // bucket-major for scan
}

// --- 3-level exclusive scan --------------------------------------------------
__global__ void scan1_kernel(const int* in, int* out, int* bsums, int n) {
    __shared__ int s[SCAN_B];
    int gid = blockIdx.x * SCAN_B + threadIdx.x;
    int x = (gid < n) ? in[gid] : 0;
    s[threadIdx.x] = x;
    __syncthreads();
    for (int off = 1; off < SCAN_B; off <<= 1) {
        int t = (threadIdx.x >= off) ? s[threadIdx.x - off] : 0;
        __syncthreads();
        s[threadIdx.x] += t;
        __syncthreads();
    }
    if (gid < n) out[gid] = s[threadIdx.x] - x;       // exclusive
    if (threadIdx.x == SCAN_B - 1) bsums[blockIdx.x] = s[SCAN_B - 1];
}

__global__ void scan2_kernel(int* bsums, int nb, int* total) {
    __shared__ int s[SCAN_B];
    int x = (threadIdx.x < nb) ? bsums[threadIdx.x] : 0;
    s[threadIdx.x] = x;
    __syncthreads();
    for (int off = 1; off < SCAN_B; off <<= 1) {
        int t = (threadIdx.x >= off) ? s[threadIdx.x - off] : 0;
        __syncthreads();
        s[threadIdx.x] += t;
        __syncthreads();
    }
    if (threadIdx.x == nb - 1) *total = s[threadIdx.x];   // inclusive grand total
    if (threadIdx.x < nb) bsums[threadIdx.x] = s[threadIdx.x] - x;
}

__global__ void scanadd_kernel(int* data, const int* __restrict__ bsums, int n) {
    int gid = blockIdx.x * blockDim.x + threadIdx.x;
    if (gid < n) data[gid] += bsums[gid / SCAN_B];
}

// --- build pass 2: bin kept edges into bucket order (LDS cursors) ------------
// record = (src | tlow<<18, weight-bits); src < 2^18, tlow 7 bits.
__global__ void bin_kernel(const int* __restrict__ src, const int* __restrict__ tgt,
                           const float* __restrict__ w, const int* __restrict__ scanned,
                           int2* __restrict__ edges, int n_edges, int n_tm1,
                           int nb, int nblk) {
    __shared__ int cur[BMAX];
    int b = blockIdx.x;
    for (int i = threadIdx.x; i < nb; i += blockDim.x)
        cur[i] = scanned[(size_t)i * nblk + b];
    __syncthreads();
    int base = b * CHUNK;
    int end = min(base + CHUNK, n_edges);
    for (int k = base + threadIdx.x; k < end; k += blockDim.x) {
        int t = tgt[k];
        if (t < n_tm1) continue;                      // dead edges (dv[:tm1]=0)
        int pos = atomicAdd(&cur[t >> BSHIFT], 1);    // LDS atomic
        edges[pos] = make_int2(src[k] | ((t & BMASK) << 18), __float_as_int(w[k]));
    }
}

// --- build pass 3: per-bucket finalize, entirely in LDS, in-place ------------
__global__ void finalize_kernel(int2* edges, const int* __restrict__ scanned,
                                int* __restrict__ row_start,
                                const int* __restrict__ total,
                                int n_neurons, int nb, int nblk) {
    __shared__ int2 buf[B4_CAP];
    __shared__ int hist[BMASK + 1], ls[BMASK + 1], cur[BMASK + 1];
    int b = blockIdx.x;
    int n_kept = *total;
    int beg = scanned[(size_t)b * nblk];
    int end = (b == nb - 1) ? n_kept : scanned[(size_t)(b + 1) * nblk];
    int n = min(end - beg, B4_CAP);

    for (int k = threadIdx.x; k < n; k += blockDim.x) buf[k] = edges[beg + k];
    if (threadIdx.x <= BMASK) hist[threadIdx.x] = 0;
    __syncthreads();
    for (int k = threadIdx.x; k < n; k += blockDim.x)
        atomicAdd(&hist[(buf[k].x >> 18) & BMASK], 1);
    __syncthreads();
    if (threadIdx.x <= BMASK) ls[threadIdx.x] = hist[threadIdx.x];
    __syncthreads();
    for (int off = 1; off <= BMASK; off <<= 1) {
        int t = (threadIdx.x <= BMASK && threadIdx.x >= off) ? ls[threadIdx.x - off] : 0;
        __syncthreads();
        if (threadIdx.x <= BMASK) ls[threadIdx.x] += t;   // inclusive
        __syncthreads();
    }
    if (threadIdx.x <= BMASK) {
        int excl = ls[threadIdx.x] - hist[threadIdx.x];
        cur[threadIdx.x] = excl;
        int t = (b << BSHIFT) + threadIdx.x;
        if (t < n_neurons) row_start[t] = beg + excl;
    }
    if (b == nb - 1 && threadIdx.x == 0) row_start[n_neurons] = n_kept;
    __syncthreads();
    for (int k = threadIdx.x; k < n; k += blockDim.x) {
        int2 r = buf[k];
        int pos = atomicAdd(&cur[(r.x >> 18) & BMASK], 1);  // LDS atomic
        edges[beg + pos] = make_int2(r.x & 0x3FFFF, r.y);
    }
}

// --- fused per-step kernel (relu-bitmask skip) -------------------------------
// Thread map: [0, gbase)               -> Tm1 region (1 thr/row + pads)
//             [gbase, gbase + 8*nrows) -> 8 lanes per gather row
// gbase mult of 64 -> `g < gbase` is wave-uniform; Tm1 waves cover 64
// consecutive neuron ids (32-aligned) for the ballot mask write; gather waves
// cover 8 consecutive rows (8-aligned bit position, never straddles a word).
__global__ void step_kernel(const int* __restrict__ row_start,
                            const int2* __restrict__ edges,
                            const float* __restrict__ vr,
                            float* __restrict__ vw,
                            float* __restrict__ tm1_f,
                            const float* __restrict__ x,     // tm1_input + k*n_tm1
                            const float* __restrict__ tau,
                            const float* __restrict__ vrest,
                            const unsigned* __restrict__ maskR,
                            unsigned* __restrict__ maskW,
                            unsigned* __restrict__ maskC,
                            int mask_words,
                            int n_neurons, int n_tm1, int gbase, int last) {
    int g = blockIdx.x * blockDim.x + threadIdx.x;

    if (g < gbase) {                         // Tm1 region (wave-uniform branch)
        if (g < mask_words) maskC[g] = 0u;   // clear the idle buffer for step k+1
        float val = 0.0f;
        bool wrote = false;
        if (g < n_tm1) {
            float cur = vr[g];               // = tm1_v at step k
            if (last) {
                val = cur;                   // ref: v[:tm1] = old tm1_v
            } else {
                float f  = tm1_f[g];
                float xk = x[g];
                float hp = xk - f;
                tm1_f[g] = f + DT * (xk - f) / TAU_HP;
                val = cur + DT * (fmaxf(hp, 0.0f) - cur) / TAU_LP;
            }
            vw[g] = val;
            wrote = true;
        }
        // ballot mask write: 64 consecutive ids per wave, 2 words
        unsigned long long bm = __ballot(wrote && (val > 0.0f));
        int l = threadIdx.x & 63;
        unsigned lo = (unsigned)(bm & 0xffffffffull);
        unsigned hi = (unsigned)(bm >> 32);
        if (l == 0 && lo)  atomicOr(&maskW[g >> 5], lo);
        if (l == 32 && hi) atomicOr(&maskW[g >> 5], hi);
        return;
    }

    int t = g - gbase;
    int row = n_tm1 + (t >> 3);
    int lane = t & 7;
    bool active = (row < n_neurons);
    float sum = 0.0f;
    float vnew = 0.0f;

    if (active) {
        int s = row_start[row];
        int e = row_start[row + 1];
        for (int p = (s & ~1) + 2 * lane; p < e; p += 16) {
            int4 q = *(const int4*)(edges + p);  // 16B aligned (p even)
            // bit==1 implies vr>0 -> relu redundant; bit==0 -> term exactly 0
            if (p >= s && ((maskR[q.x >> 5] >> (q.x & 31)) & 1u))
                sum += vr[q.x] * __int_as_float(q.y);
            if (p + 1 < e && ((maskR[q.z >> 5] >> (q.z & 31)) & 1u))
                sum += vr[q.z] * __int_as_float(q.w);
        }
    }
    sum += __shfl_xor(sum, 4);
    sum += __shfl_xor(sum, 2);
    sum += __shfl_xor(sum, 1);
    if (active && lane == 0) {
        float vi = vr[row];
        vnew = vi + DT * ((-vi + sum + vrest[row]) / tau[row]);
        vw[row] = vnew;
    }
    // wave-level mask write: 8 rows/wave at bit offset (row0&31) in {0,8,16,24}
    unsigned long long bm = __ballot(active && lane == 0 && vnew > 0.0f);
    if ((threadIdx.x & 63) == 0) {
        unsigned b8 = 0;
        #pragma unroll
        for (int i = 0; i < 8; ++i) b8 |= (unsigned)((bm >> (8 * i)) & 1ull) << i;
        if (b8) {
            int row0 = n_tm1 + (t >> 3);     // this lane's row = wave's first row
            atomicOr(&maskW[row0 >> 5], b8 << (row0 & 31));
        }
    }
}

extern "C" void kernel_launch(void* const* d_in, const int* in_sizes, int n_in,
                              void* d_out, int out_size, void* d_ws, size_t ws_size,
                              hipStream_t stream) {
    const float* tm1_input  = (const float*)d_in[0];
    const float* weights    = (const float*)d_in[1];
    const float* tau        = (const float*)d_in[2];
    const float* vrest      = (const float*)d_in[3];
    const int*   source_idx = (const int*)d_in[4];
    const int*   target_idx = (const int*)d_in[5];

    const int n_edges   = in_sizes[1];
    const int n_neurons = in_sizes[2];
    const int n_tm1     = 25000;
    const int steps     = in_sizes[0] / n_tm1;

    const int nb   = (n_neurons + BMASK) >> BSHIFT;          // 1563 buckets
    const int nblk = (n_edges + CHUNK - 1) / CHUNK;          // 196 blocks
    const int n_scan = nb * nblk;                            // 306,348
    const int mask_words = (n_neurons + 31) >> 5;            // 6250

    // Workspace (4-byte units). edges first -> 16B aligned for int4 gather.
    size_t off = 0;
    auto alloc = [&](size_t n) { size_t o = off; off += n; return o; };
    int* ws_i = (int*)d_ws;
    float* ws_f = (float*)d_ws;

    int2*     edges     = (int2*)(ws_i + alloc((size_t)(n_edges + 2) * 2));
    float*    vA        = ws_f + alloc(n_neurons);
    float*    vB        = ws_f + alloc(n_neurons);
    float*    tm1_f     = ws_f + alloc(n_tm1);
    int*      row_start = ws_i + alloc(n_neurons + 1);
    unsigned* mask3     = (unsigned*)(ws_i + alloc((size_t)3 * mask_words));
    int*      blkhist   = ws_i + alloc((size_t)n_scan);
    int*      bsums     = ws_i + alloc(SCAN_B);
    int*      total     = ws_i + alloc(1);
    (void)ws_size;

    float* out = (float*)d_out;

    const int B = 256;
    const int gridN = (n_neurons + B - 1) / B;
    const int nScanBlocks = (n_scan + SCAN_B - 1) / SCAN_B;  // 300 <= 1024
    const int gridSA = (n_scan + B - 1) / B;

    // Step-kernel thread map: Tm1 rows 1:1, then wave-aligned 8-lane groups.
    const int gbase = (n_tm1 + 63) & ~63;
    const int work  = gbase + (n_neurons - n_tm1) * 8;
    const int gridG = (work + B - 1) / B;

    // --- one-time (per launch) CSR build: zero global atomics ---
    init_kernel<<<gridN, B, 0, stream>>>(vA, tm1_f, mask3, n_neurons, n_tm1,
                                         3 * mask_words);
    bhist_kernel<<<nblk, 1024, 0, stream>>>(target_idx, blkhist, n_edges, n_tm1,
                                            nb, nblk);
    scan1_kernel<<<nScanBlocks, SCAN_B, 0, stream>>>(blkhist, blkhist, bsums, n_scan);
    scan2_kernel<<<1, SCAN_B, 0, stream>>>(bsums, nScanBlocks, total);
    scanadd_kernel<<<gridSA, B, 0, stream>>>(blkhist, bsums, n_scan);
    bin_kernel<<<nblk, 1024, 0, stream>>>(source_idx, target_idx, weights, blkhist,
                                          edges, n_edges, n_tm1, nb, nblk);
    finalize_kernel<<<nb, 1024, 0, stream>>>(edges, blkhist, row_start, total,
                                             n_neurons, nb, nblk);

    // --- steps: ONE fused kernel per step, double-buffered v, rotating mask ---
    for (int k = 0; k < steps; ++k) {
        const float* vr = (k & 1) ? vB : vA;
        float* vw = (k == steps - 1) ? out : ((k & 1) ? vA : vB);
        unsigned* mW = mask3 + (size_t)(k % 3) * mask_words;
        unsigned* mR = mask3 + (size_t)((k + 2) % 3) * mask_words;
        unsigned* mC = mask3 + (size_t)((k + 1) % 3) * mask_words;
        step_kernel<<<gridG, B, 0, stream>>>(
            row_start, edges, vr, vw, tm1_f,
            tm1_input + (size_t)k * n_tm1,
            tau, vrest, mR, mW, mC, mask_words,
            n_neurons, n_tm1, gbase, (k == steps - 1) ? 1 : 0);
    }
}

// Round 6
// 1778.876 us; speedup vs baseline: 5.3163x; 1.2253x over previous
//
#include <hip/hip_runtime.h>
#include <hip/hip_bf16.h>

#define DT 0.1f
#define TAU_HP 12.3f
#define TAU_LP 2.3f
#define SCAN_B 1024

// Radix-build parameters: bucket = tgt >> BSHIFT (128 targets/bucket).
#define BSHIFT 7
#define BMASK 127
#define BMAX 2048          // max buckets supported (n_neurons <= 262144)
#define CHUNK 32768        // edges per block in hist/bin passes
#define B4_CAP 6144        // max records per bucket in finalize
#define MWMAX 6400         // LDS mask words (supports n_neurons <= 204800)

// ---------------------------------------------------------------------------
// R1-R4: CSR-by-target, zero-atomic radix build, fused per-step kernel,
//        Tm1-target edges dropped.
// R5: 1 thr/Tm1 row + 8 lanes/gather row. NEUTRAL (1876 vs 1836)
//     -> step is NOT wave-slot-bound.
// R6: cooperative all-steps kernel. 9457us (5x WORSE). REVERTED.
// R7: relu-bitmask skip w/ GLOBAL mask reads. 2179us (+16%): the per-edge
//     mask load was itself a VMEM op on the bottlenecked path (VMEM instr
//     3->5 per 2 edges outweighed ~50% gather skip). -> step is VMEM-
//     request-rate bound.
// R8: mask moved to LDS. Stage 25KB mask once per block (coalesced),
//     bit-test via ds_read (no TA/L2). Gathers predicated: masked-off lanes
//     issue no L2 requests; all-inactive iterations skip via execz.
//     Step block size 256->1024 (amortize staging 4x; 2 blocks/CU = full
//     32-wave occupancy). Numerics bitwise-identical to R7 (passed).
// ---------------------------------------------------------------------------

__global__ void init_kernel(float* __restrict__ vA,
                            float* __restrict__ tm1_f,
                            unsigned* __restrict__ mask3,
                            int n_neurons, int n_tm1, int mask3_words) {
    int i = blockIdx.x * blockDim.x + threadIdx.x;
    if (i < n_neurons) vA[i] = 0.0f;
    if (i < n_tm1) tm1_f[i] = 0.0f;
    if (i < mask3_words) mask3[i] = 0u;
}

// --- build pass 1: per-(block,bucket) histogram (Tm1 targets dropped) --------
__global__ void bhist_kernel(const int* __restrict__ tgt, int* __restrict__ blkhist,
                             int n_edges, int n_tm1, int nb, int nblk) {
    __shared__ int hist[BMAX];
    int b = blockIdx.x;
    for (int i = threadIdx.x; i < nb; i += blockDim.x) hist[i] = 0;
    __syncthreads();
    int base = b * CHUNK;
    int end = min(base + CHUNK, n_edges);
    for (int k = base + threadIdx.x; k < end; k += blockDim.x) {
        int t = tgt[k];
        if (t >= n_tm1) atomicAdd(&hist[t >> BSHIFT], 1);
    }
    __syncthreads();
    for (int i = threadIdx.x; i < nb; i += blockDim.x)
        blkhist[(size_t)i * nblk + b] = hist[i];      // bucket-major for scan
}

// --- 3-level exclusive scan --------------------------------------------------
__global__ void scan1_kernel(const int* in, int* out, int* bsums, int n) {
    __shared__ int s[SCAN_B];
    int gid = blockIdx.x * SCAN_B + threadIdx.x;
    int x = (gid < n) ? in[gid] : 0;
    s[threadIdx.x] = x;
    __syncthreads();
    for (int off = 1; off < SCAN_B; off <<= 1) {
        int t = (threadIdx.x >= off) ? s[threadIdx.x - off] : 0;
        __syncthreads();
        s[threadIdx.x] += t;
        __syncthreads();
    }
    if (gid < n) out[gid] = s[threadIdx.x] - x;       // exclusive
    if (threadIdx.x == SCAN_B - 1) bsums[blockIdx.x] = s[SCAN_B - 1];
}

__global__ void scan2_kernel(int* bsums, int nb, int* total) {
    __shared__ int s[SCAN_B];
    int x = (threadIdx.x < nb) ? bsums[threadIdx.x] : 0;
    s[threadIdx.x] = x;
    __syncthreads();
    for (int off = 1; off < SCAN_B; off <<= 1) {
        int t = (threadIdx.x >= off) ? s[threadIdx.x - off] : 0;
        __syncthreads();
        s[threadIdx.x] += t;
        __syncthreads();
    }
    if (threadIdx.x == nb - 1) *total = s[threadIdx.x];   // inclusive grand total
    if (threadIdx.x < nb) bsums[threadIdx.x] = s[threadIdx.x] - x;
}

__global__ void scanadd_kernel(int* data, const int* __restrict__ bsums, int n) {
    int gid = blockIdx.x * blockDim.x + threadIdx.x;
    if (gid < n) data[gid] += bsums[gid / SCAN_B];
}

// --- build pass 2: bin kept edges into bucket order (LDS cursors) ------------
// record = (src | tlow<<18, weight-bits); src < 2^18, tlow 7 bits.
__global__ void bin_kernel(const int* __restrict__ src, const int* __restrict__ tgt,
                           const float* __restrict__ w, const int* __restrict__ scanned,
                           int2* __restrict__ edges, int n_edges, int n_tm1,
                           int nb, int nblk) {
    __shared__ int cur[BMAX];
    int b = blockIdx.x;
    for (int i = threadIdx.x; i < nb; i += blockDim.x)
        cur[i] = scanned[(size_t)i * nblk + b];
    __syncthreads();
    int base = b * CHUNK;
    int end = min(base + CHUNK, n_edges);
    for (int k = base + threadIdx.x; k < end; k += blockDim.x) {
        int t = tgt[k];
        if (t < n_tm1) continue;                      // dead edges (dv[:tm1]=0)
        int pos = atomicAdd(&cur[t >> BSHIFT], 1);    // LDS atomic
        edges[pos] = make_int2(src[k] | ((t & BMASK) << 18), __float_as_int(w[k]));
    }
}

// --- build pass 3: per-bucket finalize, entirely in LDS, in-place ------------
__global__ void finalize_kernel(int2* edges, const int* __restrict__ scanned,
                                int* __restrict__ row_start,
                                const int* __restrict__ total,
                                int n_neurons, int nb, int nblk) {
    __shared__ int2 buf[B4_CAP];
    __shared__ int hist[BMASK + 1], ls[BMASK + 1], cur[BMASK + 1];
    int b = blockIdx.x;
    int n_kept = *total;
    int beg = scanned[(size_t)b * nblk];
    int end = (b == nb - 1) ? n_kept : scanned[(size_t)(b + 1) * nblk];
    int n = min(end - beg, B4_CAP);

    for (int k = threadIdx.x; k < n; k += blockDim.x) buf[k] = edges[beg + k];
    if (threadIdx.x <= BMASK) hist[threadIdx.x] = 0;
    __syncthreads();
    for (int k = threadIdx.x; k < n; k += blockDim.x)
        atomicAdd(&hist[(buf[k].x >> 18) & BMASK], 1);
    __syncthreads();
    if (threadIdx.x <= BMASK) ls[threadIdx.x] = hist[threadIdx.x];
    __syncthreads();
    for (int off = 1; off <= BMASK; off <<= 1) {
        int t = (threadIdx.x <= BMASK && threadIdx.x >= off) ? ls[threadIdx.x - off] : 0;
        __syncthreads();
        if (threadIdx.x <= BMASK) ls[threadIdx.x] += t;   // inclusive
        __syncthreads();
    }
    if (threadIdx.x <= BMASK) {
        int excl = ls[threadIdx.x] - hist[threadIdx.x];
        cur[threadIdx.x] = excl;
        int t = (b << BSHIFT) + threadIdx.x;
        if (t < n_neurons) row_start[t] = beg + excl;
    }
    if (b == nb - 1 && threadIdx.x == 0) row_start[n_neurons] = n_kept;
    __syncthreads();
    for (int k = threadIdx.x; k < n; k += blockDim.x) {
        int2 r = buf[k];
        int pos = atomicAdd(&cur[(r.x >> 18) & BMASK], 1);  // LDS atomic
        edges[beg + pos] = make_int2(r.x & 0x3FFFF, r.y);
    }
}

// --- fused per-step kernel (LDS relu-bitmask skip) ---------------------------
// Thread map: [0, gbase)               -> Tm1 region (1 thr/row + pads)
//             [gbase, gbase + 8*nrows) -> 8 lanes per gather row
// gbase mult of 64 -> every wave is entirely Tm1-region or gather-region.
// Blocks containing any gather thread stage the 25KB activity mask into LDS
// (uniform per-block branch), then bit-tests are ds_reads off the VMEM path.
__global__ __launch_bounds__(1024)
void step_kernel(const int* __restrict__ row_start,
                 const int2* __restrict__ edges,
                 const float* __restrict__ vr,
                 float* __restrict__ vw,
                 float* __restrict__ tm1_f,
                 const float* __restrict__ x,     // tm1_input + k*n_tm1
                 const float* __restrict__ tau,
                 const float* __restrict__ vrest,
                 const unsigned* __restrict__ maskR,
                 unsigned* __restrict__ maskW,
                 unsigned* __restrict__ maskC,
                 int mask_words,
                 int n_neurons, int n_tm1, int gbase, int last) {
    __shared__ unsigned smask[MWMAX];
    int g = blockIdx.x * blockDim.x + threadIdx.x;

    // uniform per-block: does this block contain gather threads?
    if ((int)((blockIdx.x + 1) * blockDim.x) > gbase) {
        for (int i = threadIdx.x; i < mask_words; i += blockDim.x)
            smask[i] = maskR[i];
        __syncthreads();
    }

    if (g < gbase) {                         // Tm1 region (wave-uniform branch)
        if (g < mask_words) maskC[g] = 0u;   // clear the idle buffer for step k+1
        float val = 0.0f;
        bool wrote = false;
        if (g < n_tm1) {
            float cur = vr[g];               // = tm1_v at step k
            if (last) {
                val = cur;                   // ref: v[:tm1] = old tm1_v
            } else {
                float f  = tm1_f[g];
                float xk = x[g];
                float hp = xk - f;
                tm1_f[g] = f + DT * (xk - f) / TAU_HP;
                val = cur + DT * (fmaxf(hp, 0.0f) - cur) / TAU_LP;
            }
            vw[g] = val;
            wrote = true;
        }
        // ballot mask write: 64 consecutive ids per wave, 2 words
        unsigned long long bm = __ballot(wrote && (val > 0.0f));
        int l = threadIdx.x & 63;
        unsigned lo = (unsigned)(bm & 0xffffffffull);
        unsigned hi = (unsigned)(bm >> 32);
        if (l == 0 && lo)  atomicOr(&maskW[g >> 5], lo);
        if (l == 32 && hi) atomicOr(&maskW[g >> 5], hi);
        return;
    }

    int t = g - gbase;
    int row = n_tm1 + (t >> 3);
    int lane = t & 7;
    bool active = (row < n_neurons);
    float sum = 0.0f;
    float vnew = 0.0f;

    if (active) {
        int s = row_start[row];
        int e = row_start[row + 1];
        for (int p = (s & ~1) + 2 * lane; p < e; p += 16) {
            int4 q = *(const int4*)(edges + p);  // 16B aligned (p even)
            // bit==1 implies vr>0 -> relu redundant; bit==0 -> term exactly 0
            bool a0 = (p >= s)    && ((smask[(unsigned)q.x >> 5] >> (q.x & 31)) & 1u);
            bool a1 = (p + 1 < e) && ((smask[(unsigned)q.z >> 5] >> (q.z & 31)) & 1u);
            if (a0) sum += vr[q.x] * __int_as_float(q.y);
            if (a1) sum += vr[q.z] * __int_as_float(q.w);
        }
    }
    sum += __shfl_xor(sum, 4);
    sum += __shfl_xor(sum, 2);
    sum += __shfl_xor(sum, 1);
    if (active && lane == 0) {
        float vi = vr[row];
        vnew = vi + DT * ((-vi + sum + vrest[row]) / tau[row]);
        vw[row] = vnew;
    }
    // wave-level mask write: 8 rows/wave at bit offset (row0&31) in {0,8,16,24}
    unsigned long long bm = __ballot(active && lane == 0 && vnew > 0.0f);
    if ((threadIdx.x & 63) == 0) {
        unsigned b8 = 0;
        #pragma unroll
        for (int i = 0; i < 8; ++i) b8 |= (unsigned)((bm >> (8 * i)) & 1ull) << i;
        if (b8) {
            int row0 = n_tm1 + (t >> 3);     // this lane's row = wave's first row
            atomicOr(&maskW[row0 >> 5], b8 << (row0 & 31));
        }
    }
}

extern "C" void kernel_launch(void* const* d_in, const int* in_sizes, int n_in,
                              void* d_out, int out_size, void* d_ws, size_t ws_size,
                              hipStream_t stream) {
    const float* tm1_input  = (const float*)d_in[0];
    const float* weights    = (const float*)d_in[1];
    const float* tau        = (const float*)d_in[2];
    const float* vrest      = (const float*)d_in[3];
    const int*   source_idx = (const int*)d_in[4];
    const int*   target_idx = (const int*)d_in[5];

    const int n_edges   = in_sizes[1];
    const int n_neurons = in_sizes[2];
    const int n_tm1     = 25000;
    const int steps     = in_sizes[0] / n_tm1;

    const int nb   = (n_neurons + BMASK) >> BSHIFT;          // 1563 buckets
    const int nblk = (n_edges + CHUNK - 1) / CHUNK;          // 196 blocks
    const int n_scan = nb * nblk;                            // 306,348
    const int mask_words = (n_neurons + 31) >> 5;            // 6250 <= MWMAX

    // Workspace (4-byte units). edges first -> 16B aligned for int4 gather.
    size_t off = 0;
    auto alloc = [&](size_t n) { size_t o = off; off += n; return o; };
    int* ws_i = (int*)d_ws;
    float* ws_f = (float*)d_ws;

    int2*     edges     = (int2*)(ws_i + alloc((size_t)(n_edges + 2) * 2));
    float*    vA        = ws_f + alloc(n_neurons);
    float*    vB        = ws_f + alloc(n_neurons);
    float*    tm1_f     = ws_f + alloc(n_tm1);
    int*      row_start = ws_i + alloc(n_neurons + 1);
    unsigned* mask3     = (unsigned*)(ws_i + alloc((size_t)3 * mask_words));
    int*      blkhist   = ws_i + alloc((size_t)n_scan);
    int*      bsums     = ws_i + alloc(SCAN_B);
    int*      total     = ws_i + alloc(1);
    (void)ws_size;

    float* out = (float*)d_out;

    const int B = 256;
    const int gridN = (n_neurons + B - 1) / B;
    const int nScanBlocks = (n_scan + SCAN_B - 1) / SCAN_B;  // 300 <= 1024
    const int gridSA = (n_scan + B - 1) / B;

    // Step-kernel thread map: Tm1 rows 1:1, then wave-aligned 8-lane groups.
    const int SB = 1024;
    const int gbase = (n_tm1 + 63) & ~63;
    const int work  = gbase + (n_neurons - n_tm1) * 8;
    const int gridG = (work + SB - 1) / SB;

    // --- one-time (per launch) CSR build: zero global atomics ---
    init_kernel<<<gridN, B, 0, stream>>>(vA, tm1_f, mask3, n_neurons, n_tm1,
                                         3 * mask_words);
    bhist_kernel<<<nblk, 1024, 0, stream>>>(target_idx, blkhist, n_edges, n_tm1,
                                            nb, nblk);
    scan1_kernel<<<nScanBlocks, SCAN_B, 0, stream>>>(blkhist, blkhist, bsums, n_scan);
    scan2_kernel<<<1, SCAN_B, 0, stream>>>(bsums, nScanBlocks, total);
    scanadd_kernel<<<gridSA, B, 0, stream>>>(blkhist, bsums, n_scan);
    bin_kernel<<<nblk, 1024, 0, stream>>>(source_idx, target_idx, weights, blkhist,
                                          edges, n_edges, n_tm1, nb, nblk);
    finalize_kernel<<<nb, 1024, 0, stream>>>(edges, blkhist, row_start, total,
                                             n_neurons, nb, nblk);

    // --- steps: ONE fused kernel per step, double-buffered v, rotating mask ---
    for (int k = 0; k < steps; ++k) {
        const float* vr = (k & 1) ? vB : vA;
        float* vw = (k == steps - 1) ? out : ((k & 1) ? vA : vB);
        unsigned* mW = mask3 + (size_t)(k % 3) * mask_words;
        unsigned* mR = mask3 + (size_t)((k + 2) % 3) * mask_words;
        unsigned* mC = mask3 + (size_t)((k + 1) % 3) * mask_words;
        step_kernel<<<gridG, SB, 0, stream>>>(
            row_start, edges, vr, vw, tm1_f,
            tm1_input + (size_t)k * n_tm1,
            tau, vrest, mR, mW, mC, mask_words,
            n_neurons, n_tm1, gbase, (k == steps - 1) ? 1 : 0);
    }
}